// Round 9
// baseline (226.602 us; speedup 1.0000x reference)
//
#include <hip/hip_runtime.h>

// Integrate-and-fire forward: x (T=32, B=16, N=65536) fp32 -> y same shape.
// Per neuron: m = v + x[t]; y = (m >= 1) ? 1 : 0; v = m - y  (soft reset).
// Parallel over B*N neurons; sequential T-loop in registers. Memory-bound:
// 256 MiB traffic, mixed-stream floor ~43 us at ~6.3 TB/s (d2d copy ref).
//
// Round-8 result: ~70 us inferred (kernel dropped out of rocprof top-5; fills
// at 80 us now dominate). Round-9 changes:
//  - PF 4 -> 8: 2x outstanding reads per wave (vmcnt queue shared with stores)
//  - compile-time BN2 (shape is fixed): offsets fold to base + i*8 + t*4MiB,
//    killing per-iteration 64-bit VALU address chains (runtime fallback kept)

#define T_STEPS 32
#define PF 8  // prefetch depth (outstanding loads per wave)

typedef float f32x2 __attribute__((ext_vector_type(2)));

template <int BN2_CT>
__global__ __launch_bounds__(256) void if_fwd_kernel(const f32x2* __restrict__ x,
                                                     f32x2* __restrict__ y,
                                                     int bn2_rt) {
    const int bn2 = (BN2_CT > 0) ? BN2_CT : bn2_rt;
    const int i = blockIdx.x * blockDim.x + threadIdx.x;
    if (i >= bn2) return;

    // Prime the pipeline: PF loads in flight before any compute.
    f32x2 buf[PF];
#pragma unroll
    for (int t = 0; t < PF; ++t)
        buf[t] = __builtin_nontemporal_load(&x[(size_t)t * (size_t)bn2 + (size_t)i]);

    float vx = 0.f, vy = 0.f;

#pragma unroll
    for (int t = 0; t < T_STEPS; ++t) {
        f32x2 xt = buf[t % PF];  // compile-time index after full unroll

        // Issue the t+PF load before consuming t: keeps PF loads outstanding.
        if (t + PF < T_STEPS)
            buf[(t + PF) % PF] =
                __builtin_nontemporal_load(&x[(size_t)(t + PF) * (size_t)bn2 + (size_t)i]);

        float mx = vx + xt.x;
        float my = vy + xt.y;
        float sx = (mx >= 1.0f) ? 1.0f : 0.0f;
        float sy = (my >= 1.0f) ? 1.0f : 0.0f;
        vx = mx - sx;
        vy = my - sy;

        f32x2 s;
        s.x = sx;
        s.y = sy;
        __builtin_nontemporal_store(s, &y[(size_t)t * (size_t)bn2 + (size_t)i]);
    }
}

extern "C" void kernel_launch(void* const* d_in, const int* in_sizes, int n_in,
                              void* d_out, int out_size, void* d_ws, size_t ws_size,
                              hipStream_t stream) {
    const float* x = (const float*)d_in[0];
    float* y = (float*)d_out;

    const int total = in_sizes[0];      // T*B*N
    const int bn = total / T_STEPS;     // neurons
    const int bn2 = bn / 2;             // f32x2 lanes

    const int block = 256;
    const int grid = (bn2 + block - 1) / block;  // 2048 WGs -> 8 WG/CU

    constexpr int kBN2 = (32 * 16 * 65536 / 32) / 2;  // 524288 for the bench shape
    if (bn2 == kBN2) {
        if_fwd_kernel<kBN2><<<grid, block, 0, stream>>>((const f32x2*)x, (f32x2*)y, bn2);
    } else {
        if_fwd_kernel<0><<<grid, block, 0, stream>>>((const f32x2*)x, (f32x2*)y, bn2);
    }
}